// Round 6
// baseline (112.660 us; speedup 1.0000x reference)
//
#include <hip/hip_runtime.h>
#include <cstdint>

// Problem constants (B,S,H,D from reference)
#define BB 4
#define SS 2048
#define HH 8
#define DD 64
#define CC 64          // chunk length
#define NCK (SS/CC)    // 32 chunks
#define BHH (BB*HH)    // 32

typedef __attribute__((ext_vector_type(8))) short  short8;   // 8 bf16 (MFMA A/B frag)
typedef __attribute__((ext_vector_type(4))) float  f32x4;    // MFMA C/D frag
typedef __attribute__((ext_vector_type(4))) unsigned short us4;

__device__ __forceinline__ float elu1(float x) {
    return x > 0.f ? x + 1.f : __expf(x);
}
// fp32 -> bf16 RNE
__device__ __forceinline__ unsigned short f2bf(float f) {
    unsigned int u = __float_as_uint(f);
    u += 0x7FFFu + ((u >> 16) & 1u);
    return (unsigned short)(u >> 16);
}
__device__ __forceinline__ float bf2f(unsigned short h) {
    return __uint_as_float(((unsigned int)h) << 16);
}
// XOR swizzle for [64][64] bf16 tiles (rows 128B): spreads 16B units so
// row-varying b128 fragment reads avoid same-bank serialization. Workspace
// tiles are stored as the exact swizzled LDS byte image (gload_lds verbatim).
#define SWZ(r,c) ((r) * DD + ((c) ^ (((r) & 7) << 3)))

// 4x4 lane-transpose across lane groups M0,M1 (4 shfl_xor).
template<int M0, int M1>
__device__ __forceinline__ void xpose4(float v[4], int lane) {
    {
        const bool hi = (lane & M0) != 0;
        float x0 = hi ? v[0] : v[1];
        float x1 = hi ? v[2] : v[3];
        float r0 = __shfl_xor(x0, M0);
        float r1 = __shfl_xor(x1, M0);
        if (hi) { v[0] = r0; v[2] = r1; } else { v[1] = r0; v[3] = r1; }
    }
    {
        const bool hi = (lane & M1) != 0;
        float x0 = hi ? v[0] : v[2];
        float x1 = hi ? v[1] : v[3];
        float r0 = __shfl_xor(x0, M1);
        float r1 = __shfl_xor(x1, M1);
        if (hi) { v[0] = r0; v[1] = r1; } else { v[2] = r0; v[3] = r1; }
    }
}

__device__ __forceinline__ unsigned long long pack4bf(const float v[4]) {
    unsigned long long r;
    r  = (unsigned long long)f2bf(v[0]);
    r |= (unsigned long long)f2bf(v[1]) << 16;
    r |= (unsigned long long)f2bf(v[2]) << 32;
    r |= (unsigned long long)f2bf(v[3]) << 48;
    return r;
}

// ---------------------------------------------------------------------------
// Kernel 1: the single fp32->bf16 transform pass.
// Per chunk: stage k,v (transposed tiles in LDS), MFMA chunk state
// S^T[t][d]; emit PRE-SWIZZLED bf16 ws tiles: qb[s][d], kb[s2][d],
// vT[t][s], S_c[t][d]. grid = 1024, 256 thr, LDS 16 KB.
// ---------------------------------------------------------------------------
__global__ __launch_bounds__(256) void kv_chunk_kernel(
    const float* __restrict__ qk, const float* __restrict__ v,
    unsigned short* __restrict__ qws, unsigned short* __restrict__ kws,
    unsigned short* __restrict__ vtws, unsigned short* __restrict__ Sws)
{
    const int blk = blockIdx.x;
    const int bh = blk / NCK, c = blk % NCK;
    const int b = bh / HH, h = bh % HH;
    const int s0 = c * CC;

    __shared__ __align__(16) unsigned short kT[CC * DD];   // K^T [d][s] swz
    __shared__ __align__(16) unsigned short vT[CC * DD];   // V^T [t][s] swz

    const int tid = threadIdx.x, lane = tid & 63;

#pragma unroll
    for (int iter = 0; iter < 4; ++iter) {
        const int it = iter * 256 + tid;
        const int r = it >> 4, c0 = (it & 15) * 4;   // row s=r, cols c0..c0+3
        const int g = lane >> 4;                     // row within 4x4 block
        const int rb = r - g;                        // 4-aligned block row base

        const size_t qrow = (((size_t)(b * SS + s0 + r) * 2 + 0) * HH + h) * DD;

        // q: elu1 -> bf16 -> ws (swizzled address, coalesced per 16-lane row)
        float4 fq = *reinterpret_cast<const float4*>(qk + qrow + c0);
        us4 uq; uq.x = f2bf(elu1(fq.x)); uq.y = f2bf(elu1(fq.y));
                uq.z = f2bf(elu1(fq.z)); uq.w = f2bf(elu1(fq.w));
        *reinterpret_cast<us4*>(qws + (size_t)blk * 4096 + SWZ(r, c0)) = uq;

        // k: elu1*scale -> bf16 -> ws; transposed copy into LDS for MFMA B
        float4 fk = *reinterpret_cast<const float4*>(qk + qrow + (size_t)HH * DD + c0);
        float kv4[4] = { elu1(fk.x) * 0.125f, elu1(fk.y) * 0.125f,
                         elu1(fk.z) * 0.125f, elu1(fk.w) * 0.125f };
        us4 uk; uk.x = f2bf(kv4[0]); uk.y = f2bf(kv4[1]);
                uk.z = f2bf(kv4[2]); uk.w = f2bf(kv4[3]);
        *reinterpret_cast<us4*>(kws + (size_t)blk * 4096 + SWZ(r, c0)) = uk;
        xpose4<16, 32>(kv4, lane);                   // -> col d=c0+g, rows rb..rb+3
        *reinterpret_cast<unsigned long long*>(&kT[SWZ(c0 + g, rb)]) = pack4bf(kv4);

        // v: transposed tile in LDS (MFMA A-operand + ws dump)
        float4 fv = *reinterpret_cast<const float4*>(
            v + ((size_t)(b * SS + s0 + r) * HH + h) * DD + c0);
        float vv4[4] = { fv.x, fv.y, fv.z, fv.w };
        xpose4<16, 32>(vv4, lane);
        *reinterpret_cast<unsigned long long*>(&vT[SWZ(c0 + g, rb)]) = pack4bf(vv4);
    }
    __syncthreads();

    // dump V^T byte image (linear read of swizzled LDS -> ws stays swizzled)
#pragma unroll
    for (int j = 0; j < 2; ++j) {
        const int slot = j * 256 + tid;
        *reinterpret_cast<short8*>(vtws + (size_t)blk * 4096 + slot * 8) =
            *reinterpret_cast<const short8*>(&vT[slot * 8]);
    }

    // MFMA: S^T[t][d] = sum_s vT[t,s] * kT[d,s]
    const int lr = lane & 15, lk = (lane >> 4) * 8;
    const int wid = tid >> 6, mbase = wid * 16;
    f32x4 sc[4] = {};
#pragma unroll
    for (int kk = 0; kk < 2; ++kk) {
        short8 a = *reinterpret_cast<const short8*>(&vT[SWZ(mbase + lr, kk * 32 + lk)]);
#pragma unroll
        for (int nb = 0; nb < 4; ++nb) {
            short8 bk = *reinterpret_cast<const short8*>(&kT[SWZ(nb * 16 + lr, kk * 32 + lk)]);
            sc[nb] = __builtin_amdgcn_mfma_f32_16x16x32_bf16(a, bk, sc[nb], 0, 0, 0);
        }
    }
    // S_c write: transpose C frag on lane bits 0,1; store swizzled
    const int crow = (lane >> 4) * 4;
#pragma unroll
    for (int nb = 0; nb < 4; ++nb) {
        float cv[4] = { sc[nb][0], sc[nb][1], sc[nb][2], sc[nb][3] };
        xpose4<1, 2>(cv, lane);                      // lane: row t=crow+(lane&3), 4 d-cols
        const int t  = mbase + crow + (lane & 3);
        const int d0 = nb * 16 + (lr & ~3);
        *reinterpret_cast<unsigned long long*>(
            Sws + (size_t)blk * 4096 + SWZ(t, d0)) = pack4bf(cv);
    }
}

// ---------------------------------------------------------------------------
// Kernel 2: exclusive prefix over chunks, 4 bf16 per thread (us4), fp32 run.
// Element-wise => swizzled layout scans unchanged. grid = 128, 256 thr.
// ---------------------------------------------------------------------------
__global__ __launch_bounds__(256) void prefix_kernel(unsigned short* __restrict__ Sws)
{
    const int bh = blockIdx.x >> 2, part = blockIdx.x & 3;
    const int e = part * 1024 + threadIdx.x * 4;
    unsigned short* p = Sws + (size_t)bh * NCK * 4096 + e;

    float r0 = 0.f, r1 = 0.f, r2 = 0.f, r3 = 0.f;
#pragma unroll
    for (int c = 0; c < NCK; ++c) {
        us4 a = *reinterpret_cast<const us4*>(p + (size_t)c * 4096);
        us4 o; o.x = f2bf(r0); o.y = f2bf(r1); o.z = f2bf(r2); o.w = f2bf(r3);
        *reinterpret_cast<us4*>(p + (size_t)c * 4096) = o;   // exclusive
        r0 += bf2f(a.x); r1 += bf2f(a.y); r2 += bf2f(a.z); r3 += bf2f(a.w);
    }
}

// ---------------------------------------------------------------------------
// Kernel 3: out[s][t] = norm(s) * ( Q@S_excl + causal(Q K^T)@V )
// Staging = 8x global_load_lds(16B) verbatim byte images; 2 barriers total.
// Masked scores overlay the dead kb buffer (wave-local rows, no extra sync).
// ---------------------------------------------------------------------------
__global__ __launch_bounds__(256) void out_kernel(
    const unsigned short* __restrict__ qws, const unsigned short* __restrict__ kws,
    const unsigned short* __restrict__ vtws, const unsigned short* __restrict__ Sws,
    const float* __restrict__ nrm, const float* __restrict__ offset,
    float* __restrict__ out)
{
    const int blk = blockIdx.x;
    const int bh = blk / NCK, c = blk % NCK;
    const int b = bh / HH, h = bh % HH;
    const int s0 = c * CC;

    __shared__ __align__(16) unsigned short qb[CC * DD];   // Q  [s][d]  swz
    __shared__ __align__(16) unsigned short kb[CC * DD];   // K  [s2][d] swz -> As[s][s2]
    __shared__ __align__(16) unsigned short vT[CC * DD];   // V^T[t][s]  swz
    __shared__ __align__(16) unsigned short st[CC * DD];   // S^T[t][d]  swz

    const int tid = threadIdx.x, lane = tid & 63;
    const int wid = tid >> 6;

    // ---- stage all 4 tiles via async global->LDS (no VGPR round trip) ----
    {
        const unsigned short* gsrc[4] = {
            qws + (size_t)blk * 4096, kws + (size_t)blk * 4096,
            vtws + (size_t)blk * 4096, Sws + (size_t)blk * 4096 };
        unsigned short* ldst[4] = { qb, kb, vT, st };
#pragma unroll
        for (int bu = 0; bu < 4; ++bu) {
#pragma unroll
            for (int j = 0; j < 2; ++j) {
                const unsigned short* gp = gsrc[bu] + (size_t)(j * 256 + tid) * 8;
                __builtin_amdgcn_global_load_lds(
                    (const __attribute__((address_space(1))) void*)gp,
                    (__attribute__((address_space(3))) void*)(ldst[bu] + j * 2048 + wid * 512),
                    16, 0, 0);
            }
        }
    }

    const int lr    = lane & 15;
    const int lk    = (lane >> 4) * 8;
    const int mbase = wid * 16;
    const int crow  = (lane >> 4) * 4;

    // epilogue norm factors: issue these VGPR loads while gload_lds in flight
    const float off = offset[h];
    float nv[4];
#pragma unroll
    for (int r = 0; r < 4; ++r) {
        const int s = s0 + mbase + crow + r;
        nv[r] = nrm[(size_t)(b * SS + s) * HH + h] + off;
    }
#pragma unroll
    for (int r = 0; r < 4; ++r) nv[r] = 1.f / (1.f + __expf(nv[r]));

    __syncthreads();   // drains vmcnt (gload_lds) + lgkm

    // ---- phase 1: O = Q@S_excl ; scores = Q K^T (both k = d) ----
    f32x4 acc[4] = {};
    f32x4 as4[4] = {};
#pragma unroll
    for (int kk = 0; kk < 2; ++kk) {
        short8 aq = *reinterpret_cast<const short8*>(&qb[SWZ(mbase + lr, kk * 32 + lk)]);
#pragma unroll
        for (int nb = 0; nb < 4; ++nb) {
            short8 bs = *reinterpret_cast<const short8*>(&st[SWZ(nb * 16 + lr, kk * 32 + lk)]);
            acc[nb] = __builtin_amdgcn_mfma_f32_16x16x32_bf16(aq, bs, acc[nb], 0, 0, 0);
            short8 bk = *reinterpret_cast<const short8*>(&kb[SWZ(nb * 16 + lr, kk * 32 + lk)]);
            as4[nb] = __builtin_amdgcn_mfma_f32_16x16x32_bf16(aq, bk, as4[nb], 0, 0, 0);
        }
    }
    __syncthreads();   // all waves done reading kb before overlay

    // ---- causal-masked scores into kb as As[s][s2] (wave-local rows) ----
#pragma unroll
    for (int nb = 0; nb < 4; ++nb) {
#pragma unroll
        for (int r = 0; r < 4; ++r) {
            const int s_loc = mbase + crow + r;
            const int s2    = nb * 16 + lr;
            const float val = (s2 <= s_loc) ? as4[nb][r] : 0.f;
            kb[SWZ(s_loc, s2)] = f2bf(val);
        }
    }
    // reads below are same-wave rows; compiler inserts lgkmcnt (no barrier)

    // ---- phase 2: O += As @ V ----
#pragma unroll
    for (int kk = 0; kk < 2; ++kk) {
        short8 aa = *reinterpret_cast<const short8*>(&kb[SWZ(mbase + lr, kk * 32 + lk)]);
#pragma unroll
        for (int nb = 0; nb < 4; ++nb) {
            short8 bv = *reinterpret_cast<const short8*>(&vT[SWZ(nb * 16 + lr, kk * 32 + lk)]);
            acc[nb] = __builtin_amdgcn_mfma_f32_16x16x32_bf16(aa, bv, acc[nb], 0, 0, 0);
        }
    }

    // ---- store ----
#pragma unroll
    for (int nb = 0; nb < 4; ++nb) {
#pragma unroll
        for (int r = 0; r < 4; ++r) {
            const int s = s0 + mbase + crow + r;
            out[((size_t)(b * SS + s) * HH + h) * DD + nb * 16 + lr] = acc[nb][r] * nv[r];
        }
    }
}

// ---------------------------------------------------------------------------
extern "C" void kernel_launch(void* const* d_in, const int* in_sizes, int n_in,
                              void* d_out, int out_size, void* d_ws, size_t ws_size,
                              hipStream_t stream) {
    const float* qk     = (const float*)d_in[0];
    const float* v      = (const float*)d_in[1];
    const float* nrm    = (const float*)d_in[2];
    const float* offset = (const float*)d_in[3];
    float* out = (float*)d_out;

    const size_t TILE = (size_t)BHH * NCK * 4096;    // 4.19M bf16 per buffer
    unsigned short* qws  = (unsigned short*)d_ws;    // 8.39 MB each
    unsigned short* kws  = qws  + TILE;
    unsigned short* vtws = kws  + TILE;
    unsigned short* Sws  = vtws + TILE;

    kv_chunk_kernel<<<dim3(BHH * NCK), dim3(256), 0, stream>>>(qk, v, qws, kws, vtws, Sws);
    prefix_kernel<<<dim3(BHH * 4), dim3(256), 0, stream>>>(Sws);
    out_kernel<<<dim3(BHH * NCK), dim3(256), 0, stream>>>(qws, kws, vtws, Sws, nrm, offset, out);
}